// Round 13
// baseline (125.075 us; speedup 1.0000x reference)
//
#include <hip/hip_runtime.h>
#include <math.h>

typedef __bf16 bf16;
typedef __bf16 bf16x8 __attribute__((ext_vector_type(8)));
typedef float f32x4 __attribute__((ext_vector_type(4)));
typedef unsigned int u32;
typedef unsigned long long u64;

#define MFMA_BF16(a, b, c) __builtin_amdgcn_mfma_f32_16x16x32_bf16((a), (b), (c), 0, 0, 0)

static constexpr int kB = 2;
static constexpr int kS = 2048;
static constexpr int kD = 512;
static constexpr int kH = 8;
static constexpr int kDK = 64;
static constexpr int kTileBytes = 8192;          // 64 keys x 64 dk x bf16
static constexpr int kBhBytes = 32 * kTileBytes; // 256KB per bh

// ---------------- helpers ----------------
__device__ __forceinline__ void cvt16(const float* __restrict__ p, bf16x8& v0, bf16x8& v1) {
  const float4 fA = ((const float4*)p)[0];
  const float4 fB = ((const float4*)p)[1];
  const float4 fC = ((const float4*)p)[2];
  const float4 fD = ((const float4*)p)[3];
  v0[0] = (bf16)fA.x; v0[1] = (bf16)fA.y; v0[2] = (bf16)fA.z; v0[3] = (bf16)fA.w;
  v0[4] = (bf16)fB.x; v0[5] = (bf16)fB.y; v0[6] = (bf16)fB.z; v0[7] = (bf16)fB.w;
  v1[0] = (bf16)fC.x; v1[1] = (bf16)fC.y; v1[2] = (bf16)fC.z; v1[3] = (bf16)fC.w;
  v1[4] = (bf16)fD.x; v1[5] = (bf16)fD.y; v1[6] = (bf16)fD.z; v1[7] = (bf16)fD.w;
}
__device__ __forceinline__ void cvt8(const float* __restrict__ p, bf16x8& v0) {
  const float4 fA = ((const float4*)p)[0];
  const float4 fB = ((const float4*)p)[1];
  v0[0] = (bf16)fA.x; v0[1] = (bf16)fA.y; v0[2] = (bf16)fA.z; v0[3] = (bf16)fA.w;
  v0[4] = (bf16)fB.x; v0[5] = (bf16)fB.y; v0[6] = (bf16)fB.z; v0[7] = (bf16)fB.w;
}

// ---------------- mask preprocess (runs as proj z=3 slice, 1 block) ----------
__device__ void detect_body(const unsigned char* __restrict__ m, u32* __restrict__ bm) {
  __shared__ int sh;
  const int tid = threadIdx.x;
  if (tid == 0) sh = 0;
  __syncthreads();
  const u32* mw = (const u32*)m;
  int any = 0;
  #pragma unroll
  for (int i = tid; i < kB * kS / 4; i += 256) {
    if (mw[i] & 0xFFFFFF00u) any = 1;
  }
  if (any) atomicOr(&sh, 1);
  __syncthreads();
  const bool as_bool = (sh != 0);
  for (int wi = tid; wi < kB * kS / 32; wi += 256) {
    u32 word = 0;
    if (as_bool) {
      #pragma unroll
      for (int c = 0; c < 8; c++) {
        const u32 x = mw[wi * 8 + c];
        word |= ((x & 1u) | ((x >> 7) & 2u) | ((x >> 14) & 4u) | ((x >> 21) & 8u)) << (c * 4);
      }
    } else {
      #pragma unroll
      for (int c = 0; c < 32; c++)
        word |= ((((const int*)m)[wi * 32 + c]) ? 1u : 0u) << c;
    }
    bm[wi] = word;
  }
}

// ---------------- GEMM: C[m][n] = sum_k A[m][k] * W[n][k] ----------------
template <bool A_IS_F32, int MODE, int BM, int BN>
__device__ __forceinline__ void gemm_body(const void* __restrict__ Aptr,
                                          const float* __restrict__ Wptr,
                                          void* __restrict__ dst) {
  constexpr bool TRANS = (MODE != 2);
  constexpr int WM = BM / 2, WN = BN / 2;
  constexpr int MI = WM / 16, NI = WN / 16;
  __shared__ bf16 As[BM][40];
  __shared__ bf16 Bs[BN][40];

  const int tid = threadIdx.x;
  const int lane = tid & 63;
  const int w = tid >> 6;
  const int wr = w & 1, wc = w >> 1;
  const int l16 = lane & 15, g = lane >> 4;

  const int m_tile = blockIdx.x * BM;
  const int n_tile = blockIdx.y * BN;

  f32x4 acc[MI][NI] = {};

  for (int k0 = 0; k0 < kD; k0 += 32) {
    {
      constexpr int tpr = 256 / BM;
      const int r = tid / tpr, c = (tid % tpr) * (32 / tpr);
      if constexpr (A_IS_F32) {
        const float* ap = (const float*)Aptr + (size_t)(m_tile + r) * kD + k0 + c;
        if constexpr (tpr == 2) {
          bf16x8 v0, v1; cvt16(ap, v0, v1);
          *(bf16x8*)&As[r][c] = v0; *(bf16x8*)&As[r][c + 8] = v1;
        } else {
          bf16x8 v0; cvt8(ap, v0);
          *(bf16x8*)&As[r][c] = v0;
        }
      } else {
        const bf16* ap = (const bf16*)Aptr + (size_t)(m_tile + r) * kD + k0 + c;
        if constexpr (tpr == 2) {
          *(bf16x8*)&As[r][c] = *(const bf16x8*)ap;
          *(bf16x8*)&As[r][c + 8] = *(const bf16x8*)(ap + 8);
        } else {
          *(bf16x8*)&As[r][c] = *(const bf16x8*)ap;
        }
      }
    }
    {
      constexpr int tpr = 256 / BN;
      const int r = tid / tpr, c = (tid % tpr) * (32 / tpr);
      const float* bp = Wptr + (size_t)(n_tile + r) * kD + k0 + c;
      if constexpr (tpr == 2) {
        bf16x8 v0, v1; cvt16(bp, v0, v1);
        *(bf16x8*)&Bs[r][c] = v0; *(bf16x8*)&Bs[r][c + 8] = v1;
      } else {
        bf16x8 v0; cvt8(bp, v0);
        *(bf16x8*)&Bs[r][c] = v0;
      }
    }
    __syncthreads();

    bf16x8 a[MI], bfr[NI];
    #pragma unroll
    for (int i = 0; i < MI; i++)
      a[i] = *(const bf16x8*)&As[wr * WM + i * 16 + l16][g * 8];
    #pragma unroll
    for (int i = 0; i < NI; i++)
      bfr[i] = *(const bf16x8*)&Bs[wc * WN + i * 16 + l16][g * 8];
    #pragma unroll
    for (int mi = 0; mi < MI; mi++)
      #pragma unroll
      for (int ni = 0; ni < NI; ni++) {
        if constexpr (TRANS)
          acc[mi][ni] = MFMA_BF16(bfr[ni], a[mi], acc[mi][ni]);  // C^T
        else
          acc[mi][ni] = MFMA_BF16(a[mi], bfr[ni], acc[mi][ni]);
      }
    __syncthreads();
  }

  #pragma unroll
  for (int mi = 0; mi < MI; mi++) {
    #pragma unroll
    for (int ni = 0; ni < NI; ni++) {
      const f32x4 v = acc[mi][ni];
      if constexpr (TRANS) {
        const int gm = m_tile + wr * WM + mi * 16 + l16;
        const int gn0 = n_tile + wc * WN + ni * 16 + g * 4;
        if constexpr (MODE == 3) {
          *(float4*)&((float*)dst)[(size_t)gm * kD + gn0] =
              (float4){v[0], v[1], v[2], v[3]};
        } else {
          const int bi = gm >> 11;
          const int s = gm & (kS - 1);
          const int h = gn0 >> 6;
          const int dk0 = gn0 & (kDK - 1);
          union { bf16 hh[4]; u64 u; } pk;
          pk.hh[0] = (bf16)v[0]; pk.hh[1] = (bf16)v[1];
          pk.hh[2] = (bf16)v[2]; pk.hh[3] = (bf16)v[3];
          if constexpr (MODE == 0) {
            *(u64*)&((bf16*)dst)[(((size_t)bi * kH + h) * kS + s) * kDK + dk0] = pk.u;
          } else {
            char* base = (char*)dst + (size_t)(bi * kH + h) * kBhBytes + (s >> 6) * kTileBytes;
            *(u64*)(base + (s & 63) * 128 + ((dk0 * 2) ^ ((s & 7) << 4))) = pk.u;
          }
        }
      } else {  // MODE 2
        const int gm0 = m_tile + wr * WM + mi * 16 + g * 4;
        const int gn = n_tile + wc * WN + ni * 16 + l16;
        const int bi = gm0 >> 11;
        const int s0 = gm0 & (kS - 1);
        const int h = gn >> 6;
        const int dk = gn & (kDK - 1);
        union { bf16 hh[4]; u64 u; } pk;
        pk.hh[0] = (bf16)v[0]; pk.hh[1] = (bf16)v[1];
        pk.hh[2] = (bf16)v[2]; pk.hh[3] = (bf16)v[3];
        char* base = (char*)dst + (size_t)(bi * kH + h) * kBhBytes + (s0 >> 6) * kTileBytes;
        *(u64*)(base + dk * 128 + (((s0 & 63) * 2) ^ ((dk & 7) << 4))) = pk.u;
      }
    }
  }
}

__global__ __launch_bounds__(256) void proj_kernel(
    const float* __restrict__ q, const float* __restrict__ k, const float* __restrict__ v,
    const float* __restrict__ Wq, const float* __restrict__ Wk, const float* __restrict__ Wv,
    bf16* __restrict__ qw, bf16* __restrict__ kw, bf16* __restrict__ vtw,
    const unsigned char* __restrict__ mask, u32* __restrict__ bm) {
  const int z = blockIdx.z;
  if (z == 3) {
    if (blockIdx.x == 0 && blockIdx.y == 0) detect_body(mask, bm);
    return;
  }
  if (z == 0) gemm_body<true, 0, 64, 128>(q, Wq, qw);
  else if (z == 1) gemm_body<true, 1, 64, 128>(k, Wk, kw);
  else gemm_body<true, 2, 64, 128>(v, Wv, vtw);
}

__global__ __launch_bounds__(256) void out_kernel(const bf16* __restrict__ x,
                                                  const float* __restrict__ Wo,
                                                  float* __restrict__ out) {
  gemm_body<false, 3, 128, 64>(x, Wo, out);
}

// ---------------- attention: 8-wave blocks, 128 q-rows, 128-key phases -------
// 256 blocks x 512 thr (1/CU). KV DMA'd ONCE per block-phase (32 KB shared by
// 8 waves) -> per-CU phase bytes 96 KB vs r12's 128 KB. 16 phases, 1 barrier
// pair/phase. FIFO queue: [bias(t) 8, dma(t+1) 4, bias(t+1) 8] -> mid-phase
// vmcnt(12) retires bias(t); end-phase vmcnt(8) retires dma(t+1).
__global__ __launch_bounds__(512, 1) void attn_kernel(
    const bf16* __restrict__ qw, const char* __restrict__ kw,
    const char* __restrict__ vt, const float* __restrict__ bias,
    const u32* __restrict__ bmask, bf16* __restrict__ xw) {
  __shared__ char KV[2][2][2 * kTileBytes];  // [buf][K/V][128-key tile] = 64 KB
  __shared__ u32 Ps[8][16][36];              // per-wave packed P^T rows = 18.4 KB
  __shared__ u32 mask_lds[64];

  const int tid = threadIdx.x;
  const int lane = tid & 63;
  const int w = tid >> 6;                // 0..7
  const int l16 = lane & 15, g = lane >> 4;

  // XCD mapping: 2 bh per XCD; 16 q-blocks (128 rows each) per bh.
  const int bid = blockIdx.x;            // 0..255
  const int xcd = bid & 7;
  const int j = bid >> 3;                // 0..31
  const int bh = xcd * 2 + (j >> 4);     // 0..15
  const int qb = j & 15;                 // 0..15
  const int b = bh >> 3;
  const int hh = bh & 7;
  const int qr0 = qb * 128 + w * 16;

  if (tid < 64) mask_lds[tid] = bmask[b * 64 + tid];
  __syncthreads();

  const bf16* qrow = qw + ((size_t)bh * kS + qr0 + l16) * kDK;
  const bf16x8 aq0 = *(const bf16x8*)(qrow + g * 8);
  const bf16x8 aq1 = *(const bf16x8*)(qrow + 32 + g * 8);

  const float* brow = bias + ((size_t)bh * kS + qr0 + l16) * kS;
  const char* ktile = kw + (size_t)bh * kBhBytes;
  const char* vtile = vt + (size_t)bh * kBhBytes;

  f32x4 o[4] = {};
  float m_run = -__builtin_inff();
  float l_run = 0.f;
  const int swz = (l16 & 7) << 4;

  // 4 instr/wave: chunk c = i*8 + w (1 KB each); c<16 -> K, else V.
  auto dma_tile = [&](int t128, int nb) {
    const char* kg = ktile + (size_t)t128 * 2 * kTileBytes;
    const char* vg = vtile + (size_t)t128 * 2 * kTileBytes;
    __builtin_amdgcn_global_load_lds(
        (const __attribute__((address_space(1))) void*)(kg + w * 1024 + lane * 16),
        (__attribute__((address_space(3))) void*)&KV[nb][0][w * 1024], 16, 0, 0);
    __builtin_amdgcn_global_load_lds(
        (const __attribute__((address_space(1))) void*)(kg + (8 + w) * 1024 + lane * 16),
        (__attribute__((address_space(3))) void*)&KV[nb][0][(8 + w) * 1024], 16, 0, 0);
    __builtin_amdgcn_global_load_lds(
        (const __attribute__((address_space(1))) void*)(vg + w * 1024 + lane * 16),
        (__attribute__((address_space(3))) void*)&KV[nb][1][w * 1024], 16, 0, 0);
    __builtin_amdgcn_global_load_lds(
        (const __attribute__((address_space(1))) void*)(vg + (8 + w) * 1024 + lane * 16),
        (__attribute__((address_space(3))) void*)&KV[nb][1][(8 + w) * 1024], 16, 0, 0);
  };
  auto load_bias8 = [&](f32x4 (&bv)[8], int t128) {
    const float* p0 = brow + t128 * 128 + g * 4;
    asm volatile("global_load_dwordx4 %0, %1, off nt" : "=v"(bv[0]) : "v"(p0));
    asm volatile("global_load_dwordx4 %0, %1, off nt" : "=v"(bv[1]) : "v"(p0 + 16));
    asm volatile("global_load_dwordx4 %0, %1, off nt" : "=v"(bv[2]) : "v"(p0 + 32));
    asm volatile("global_load_dwordx4 %0, %1, off nt" : "=v"(bv[3]) : "v"(p0 + 48));
    asm volatile("global_load_dwordx4 %0, %1, off nt" : "=v"(bv[4]) : "v"(p0 + 64));
    asm volatile("global_load_dwordx4 %0, %1, off nt" : "=v"(bv[5]) : "v"(p0 + 80));
    asm volatile("global_load_dwordx4 %0, %1, off nt" : "=v"(bv[6]) : "v"(p0 + 96));
    asm volatile("global_load_dwordx4 %0, %1, off nt" : "=v"(bv[7]) : "v"(p0 + 112));
  };

  auto phase = [&](int t, f32x4 (&bc)[8], f32x4 (&bn)[8]) {
    const int cur = t & 1, nxt = cur ^ 1;
    const int tp = (t + 1 > 15) ? 15 : t + 1;
    dma_tile(tp, nxt);
    load_bias8(bn, tp);

    f32x4 sf[8];
    #pragma unroll
    for (int hb = 0; hb < 2; hb++) {
      const char* kb0 = &KV[cur][0][hb * kTileBytes];
      bf16x8 kf[4][2];
      #pragma unroll
      for (int nf = 0; nf < 4; nf++) {
        const int r = nf * 16 + l16;
        #pragma unroll
        for (int h = 0; h < 2; h++)
          kf[nf][h] = *(const bf16x8*)(kb0 + r * 128 + ((g * 16 + h * 64) ^ swz));
      }
      __builtin_amdgcn_s_setprio(1);
      #pragma unroll
      for (int nf = 0; nf < 4; nf++) {
        f32x4 z = {};
        z = MFMA_BF16(kf[nf][0], aq0, z);
        z = MFMA_BF16(kf[nf][1], aq1, z);
        sf[hb * 4 + nf] = z;
      }
      __builtin_amdgcn_s_setprio(0);
    }

    // retire bias(t): queue = [bias(t) 8, dma(t+1) 4, bias(t+1) 8]
    asm volatile("s_waitcnt vmcnt(12)" ::: "memory");
    __builtin_amdgcn_sched_barrier(0);

    const u32 wm0 = mask_lds[4 * t], wm1 = mask_lds[4 * t + 1];
    const u32 wm2 = mask_lds[4 * t + 2], wm3 = mask_lds[4 * t + 3];
    float p[8][4];
    float tmax = -__builtin_inff();
    #pragma unroll
    for (int nf = 0; nf < 8; nf++) {
      const u32 wsel = (nf < 2) ? wm0 : (nf < 4) ? wm1 : (nf < 6) ? wm2 : wm3;
      #pragma unroll
      for (int r = 0; r < 4; r++) {
        float sv = sf[nf][r] * 0.125f - bc[nf][r];
        const int bp = (nf & 1) * 16 + g * 4 + r;
        if ((wsel >> bp) & 1) sv = -__builtin_inff();
        p[nf][r] = sv;
        tmax = fmaxf(tmax, sv);
      }
    }
    tmax = fmaxf(tmax, __shfl_xor(tmax, 16, 64));
    tmax = fmaxf(tmax, __shfl_xor(tmax, 32, 64));

    const float mnew = fmaxf(m_run, tmax);
    const float scale = (m_run == -__builtin_inff()) ? 0.f : __expf(m_run - mnew);
    const float mexp = (mnew == -__builtin_inff()) ? 0.f : mnew;
    float psum = 0.f;
    #pragma unroll
    for (int nf = 0; nf < 8; nf++)
      #pragma unroll
      for (int r = 0; r < 4; r++) {
        const float pv = __expf(p[nf][r] - mexp);
        p[nf][r] = pv;
        psum += pv;
      }
    psum += __shfl_xor(psum, 16, 64);
    psum += __shfl_xor(psum, 32, 64);
    m_run = mnew;
    l_run = l_run * scale + psum;
    #pragma unroll
    for (int ni = 0; ni < 4; ni++) o[ni] *= scale;

    #pragma unroll
    for (int hb = 0; hb < 2; hb++) {
      #pragma unroll
      for (int nf = 0; nf < 4; nf++) {
        union { bf16 h2[2]; u32 u; } c0, c1;
        c0.h2[0] = (bf16)p[hb * 4 + nf][0]; c0.h2[1] = (bf16)p[hb * 4 + nf][1];
        c1.h2[0] = (bf16)p[hb * 4 + nf][2]; c1.h2[1] = (bf16)p[hb * 4 + nf][3];
        Ps[w][l16][nf * 8 + g * 2] = c0.u;
        Ps[w][l16][nf * 8 + g * 2 + 1] = c1.u;
      }
      asm volatile("s_waitcnt lgkmcnt(0)" ::: "memory");
      const char* vb0 = &KV[cur][1][hb * kTileBytes];
      bf16x8 vf[2][4];
      #pragma unroll
      for (int kb2 = 0; kb2 < 2; kb2++)
        #pragma unroll
        for (int ni = 0; ni < 4; ni++) {
          const int d = ni * 16 + l16;
          vf[kb2][ni] = *(const bf16x8*)(vb0 + d * 128 + ((kb2 * 64 + g * 16) ^ swz));
        }
      __builtin_amdgcn_s_setprio(1);
      #pragma unroll
      for (int kb2 = 0; kb2 < 2; kb2++) {
        const bf16x8 pb = *(const bf16x8*)&Ps[w][l16][kb2 * 16 + g * 4];
        #pragma unroll
        for (int ni = 0; ni < 4; ni++)
          o[ni] = MFMA_BF16(vf[kb2][ni], pb, o[ni]);
      }
      __builtin_amdgcn_s_setprio(0);
    }

    // retire dma(t+1); bias(t+1) stays in flight across the barrier
    asm volatile("s_waitcnt vmcnt(8)" ::: "memory");
    __builtin_amdgcn_s_barrier();
    __builtin_amdgcn_sched_barrier(0);
  };

  f32x4 bc[8], bn[8];
  dma_tile(0, 0);
  load_bias8(bc, 0);
  asm volatile("s_waitcnt vmcnt(8)" ::: "memory");
  __builtin_amdgcn_s_barrier();
  __builtin_amdgcn_sched_barrier(0);

  for (int t = 0; t < 16; t += 2) {
    phase(t, bc, bn);
    phase(t + 1, bn, bc);
  }

  const float inv = (l_run > 0.f) ? 1.f / l_run : 0.f;
  bf16* dstp = xw + ((size_t)b * kS + qr0 + l16) * kD + hh * kDK;
  #pragma unroll
  for (int ni = 0; ni < 4; ni++) {
    union { bf16 h2[2]; u32 u; } c0, c1;
    c0.h2[0] = (bf16)(o[ni][0] * inv); c0.h2[1] = (bf16)(o[ni][1] * inv);
    c1.h2[0] = (bf16)(o[ni][2] * inv); c1.h2[1] = (bf16)(o[ni][3] * inv);
    *(u32*)&dstp[ni * 16 + g * 4] = c0.u;
    *(u32*)&dstp[ni * 16 + g * 4 + 2] = c1.u;
  }
}

extern "C" void kernel_launch(void* const* d_in, const int* in_sizes, int n_in,
                              void* d_out, int out_size, void* d_ws, size_t ws_size,
                              hipStream_t stream) {
  (void)in_sizes; (void)n_in; (void)out_size; (void)ws_size;
  const float* query = (const float*)d_in[0];
  const float* key_in = (const float*)d_in[1];
  const float* value = (const float*)d_in[2];
  const float* attnw = (const float*)d_in[3];
  const unsigned char* mask = (const unsigned char*)d_in[4];
  const float* Wq = (const float*)d_in[5];
  const float* Wk = (const float*)d_in[6];
  const float* Wv = (const float*)d_in[7];
  const float* Wo = (const float*)d_in[8];

  const size_t nqkv = (size_t)kB * kH * kS * kDK;
  size_t off = 0;
  auto alloc = [&](size_t bytes) {
    void* p = (char*)d_ws + off;
    off = (off + bytes + 255) & ~(size_t)255;
    return p;
  };
  u32* bm = (u32*)alloc(kB * kS / 32 * 4);
  bf16* q_ws = (bf16*)alloc(nqkv * 2);
  char* k_ws = (char*)alloc(nqkv * 2);
  char* vt_ws = (char*)alloc(nqkv * 2);
  bf16* x_ws = (bf16*)alloc((size_t)kB * kS * kD * 2);

  proj_kernel<<<dim3(64, 4, 4), dim3(256), 0, stream>>>(query, key_in, value, Wq, Wk, Wv,
                                                        q_ws, (bf16*)k_ws, (bf16*)vt_ws,
                                                        mask, bm);
  attn_kernel<<<dim3(256), dim3(512), 0, stream>>>(q_ws, k_ws, vt_ws, attnw, bm, x_ws);
  out_kernel<<<dim3(32, 8), dim3(256), 0, stream>>>(x_ws, Wo, (float*)d_out);
}

// Round 14
// 120.986 us; speedup vs baseline: 1.0338x; 1.0338x over previous
//
#include <hip/hip_runtime.h>
#include <math.h>

typedef __bf16 bf16;
typedef __bf16 bf16x8 __attribute__((ext_vector_type(8)));
typedef float f32x4 __attribute__((ext_vector_type(4)));
typedef unsigned int u32;
typedef unsigned long long u64;

#define MFMA_BF16(a, b, c) __builtin_amdgcn_mfma_f32_16x16x32_bf16((a), (b), (c), 0, 0, 0)

static constexpr int kB = 2;
static constexpr int kS = 2048;
static constexpr int kD = 512;
static constexpr int kH = 8;
static constexpr int kDK = 64;
static constexpr int kTileBytes = 8192;          // 64 keys x 64 dk x bf16
static constexpr int kBhBytes = 32 * kTileBytes; // 256KB per bh

// ---------------- helpers ----------------
__device__ __forceinline__ void cvt16(const float* __restrict__ p, bf16x8& v0, bf16x8& v1) {
  const float4 fA = ((const float4*)p)[0];
  const float4 fB = ((const float4*)p)[1];
  const float4 fC = ((const float4*)p)[2];
  const float4 fD = ((const float4*)p)[3];
  v0[0] = (bf16)fA.x; v0[1] = (bf16)fA.y; v0[2] = (bf16)fA.z; v0[3] = (bf16)fA.w;
  v0[4] = (bf16)fB.x; v0[5] = (bf16)fB.y; v0[6] = (bf16)fB.z; v0[7] = (bf16)fB.w;
  v1[0] = (bf16)fC.x; v1[1] = (bf16)fC.y; v1[2] = (bf16)fC.z; v1[3] = (bf16)fC.w;
  v1[4] = (bf16)fD.x; v1[5] = (bf16)fD.y; v1[6] = (bf16)fD.z; v1[7] = (bf16)fD.w;
}
__device__ __forceinline__ void cvt8(const float* __restrict__ p, bf16x8& v0) {
  const float4 fA = ((const float4*)p)[0];
  const float4 fB = ((const float4*)p)[1];
  v0[0] = (bf16)fA.x; v0[1] = (bf16)fA.y; v0[2] = (bf16)fA.z; v0[3] = (bf16)fA.w;
  v0[4] = (bf16)fB.x; v0[5] = (bf16)fB.y; v0[6] = (bf16)fB.z; v0[7] = (bf16)fB.w;
}

// ---------------- mask preprocess (runs as proj z=3 slice, 1 block) ----------
__device__ void detect_body(const unsigned char* __restrict__ m, u32* __restrict__ bm) {
  __shared__ int sh;
  const int tid = threadIdx.x;
  if (tid == 0) sh = 0;
  __syncthreads();
  const u32* mw = (const u32*)m;
  int any = 0;
  #pragma unroll
  for (int i = tid; i < kB * kS / 4; i += 256) {
    if (mw[i] & 0xFFFFFF00u) any = 1;
  }
  if (any) atomicOr(&sh, 1);
  __syncthreads();
  const bool as_bool = (sh != 0);
  for (int wi = tid; wi < kB * kS / 32; wi += 256) {
    u32 word = 0;
    if (as_bool) {
      #pragma unroll
      for (int c = 0; c < 8; c++) {
        const u32 x = mw[wi * 8 + c];
        word |= ((x & 1u) | ((x >> 7) & 2u) | ((x >> 14) & 4u) | ((x >> 21) & 8u)) << (c * 4);
      }
    } else {
      #pragma unroll
      for (int c = 0; c < 32; c++)
        word |= ((((const int*)m)[wi * 32 + c]) ? 1u : 0u) << c;
    }
    bm[wi] = word;
  }
}

// ---------------- GEMM: C[m][n] = sum_k A[m][k] * W[n][k] ----------------
template <bool A_IS_F32, int MODE, int BM, int BN>
__device__ __forceinline__ void gemm_body(const void* __restrict__ Aptr,
                                          const float* __restrict__ Wptr,
                                          void* __restrict__ dst) {
  constexpr bool TRANS = (MODE != 2);
  constexpr int WM = BM / 2, WN = BN / 2;
  constexpr int MI = WM / 16, NI = WN / 16;
  __shared__ bf16 As[BM][40];
  __shared__ bf16 Bs[BN][40];

  const int tid = threadIdx.x;
  const int lane = tid & 63;
  const int w = tid >> 6;
  const int wr = w & 1, wc = w >> 1;
  const int l16 = lane & 15, g = lane >> 4;

  const int m_tile = blockIdx.x * BM;
  const int n_tile = blockIdx.y * BN;

  f32x4 acc[MI][NI] = {};

  for (int k0 = 0; k0 < kD; k0 += 32) {
    {
      constexpr int tpr = 256 / BM;
      const int r = tid / tpr, c = (tid % tpr) * (32 / tpr);
      if constexpr (A_IS_F32) {
        const float* ap = (const float*)Aptr + (size_t)(m_tile + r) * kD + k0 + c;
        if constexpr (tpr == 2) {
          bf16x8 v0, v1; cvt16(ap, v0, v1);
          *(bf16x8*)&As[r][c] = v0; *(bf16x8*)&As[r][c + 8] = v1;
        } else {
          bf16x8 v0; cvt8(ap, v0);
          *(bf16x8*)&As[r][c] = v0;
        }
      } else {
        const bf16* ap = (const bf16*)Aptr + (size_t)(m_tile + r) * kD + k0 + c;
        if constexpr (tpr == 2) {
          *(bf16x8*)&As[r][c] = *(const bf16x8*)ap;
          *(bf16x8*)&As[r][c + 8] = *(const bf16x8*)(ap + 8);
        } else {
          *(bf16x8*)&As[r][c] = *(const bf16x8*)ap;
        }
      }
    }
    {
      constexpr int tpr = 256 / BN;
      const int r = tid / tpr, c = (tid % tpr) * (32 / tpr);
      const float* bp = Wptr + (size_t)(n_tile + r) * kD + k0 + c;
      if constexpr (tpr == 2) {
        bf16x8 v0, v1; cvt16(bp, v0, v1);
        *(bf16x8*)&Bs[r][c] = v0; *(bf16x8*)&Bs[r][c + 8] = v1;
      } else {
        bf16x8 v0; cvt8(bp, v0);
        *(bf16x8*)&Bs[r][c] = v0;
      }
    }
    __syncthreads();

    bf16x8 a[MI], bfr[NI];
    #pragma unroll
    for (int i = 0; i < MI; i++)
      a[i] = *(const bf16x8*)&As[wr * WM + i * 16 + l16][g * 8];
    #pragma unroll
    for (int i = 0; i < NI; i++)
      bfr[i] = *(const bf16x8*)&Bs[wc * WN + i * 16 + l16][g * 8];
    #pragma unroll
    for (int mi = 0; mi < MI; mi++)
      #pragma unroll
      for (int ni = 0; ni < NI; ni++) {
        if constexpr (TRANS)
          acc[mi][ni] = MFMA_BF16(bfr[ni], a[mi], acc[mi][ni]);  // C^T
        else
          acc[mi][ni] = MFMA_BF16(a[mi], bfr[ni], acc[mi][ni]);
      }
    __syncthreads();
  }

  #pragma unroll
  for (int mi = 0; mi < MI; mi++) {
    #pragma unroll
    for (int ni = 0; ni < NI; ni++) {
      const f32x4 v = acc[mi][ni];
      if constexpr (TRANS) {
        const int gm = m_tile + wr * WM + mi * 16 + l16;
        const int gn0 = n_tile + wc * WN + ni * 16 + g * 4;
        if constexpr (MODE == 3) {
          *(float4*)&((float*)dst)[(size_t)gm * kD + gn0] =
              (float4){v[0], v[1], v[2], v[3]};
        } else {
          const int bi = gm >> 11;
          const int s = gm & (kS - 1);
          const int h = gn0 >> 6;
          const int dk0 = gn0 & (kDK - 1);
          union { bf16 hh[4]; u64 u; } pk;
          pk.hh[0] = (bf16)v[0]; pk.hh[1] = (bf16)v[1];
          pk.hh[2] = (bf16)v[2]; pk.hh[3] = (bf16)v[3];
          if constexpr (MODE == 0) {
            *(u64*)&((bf16*)dst)[(((size_t)bi * kH + h) * kS + s) * kDK + dk0] = pk.u;
          } else {
            char* base = (char*)dst + (size_t)(bi * kH + h) * kBhBytes + (s >> 6) * kTileBytes;
            *(u64*)(base + (s & 63) * 128 + ((dk0 * 2) ^ ((s & 7) << 4))) = pk.u;
          }
        }
      } else {  // MODE 2
        const int gm0 = m_tile + wr * WM + mi * 16 + g * 4;
        const int gn = n_tile + wc * WN + ni * 16 + l16;
        const int bi = gm0 >> 11;
        const int s0 = gm0 & (kS - 1);
        const int h = gn >> 6;
        const int dk = gn & (kDK - 1);
        union { bf16 hh[4]; u64 u; } pk;
        pk.hh[0] = (bf16)v[0]; pk.hh[1] = (bf16)v[1];
        pk.hh[2] = (bf16)v[2]; pk.hh[3] = (bf16)v[3];
        char* base = (char*)dst + (size_t)(bi * kH + h) * kBhBytes + (s0 >> 6) * kTileBytes;
        *(u64*)(base + dk * 128 + (((s0 & 63) * 2) ^ ((dk & 7) << 4))) = pk.u;
      }
    }
  }
}

// proj: 64x128 tiles, grid (64,4,4); z=3 is the fused mask-detect slice.
__global__ __launch_bounds__(256) void proj_kernel(
    const float* __restrict__ q, const float* __restrict__ k, const float* __restrict__ v,
    const float* __restrict__ Wq, const float* __restrict__ Wk, const float* __restrict__ Wv,
    bf16* __restrict__ qw, bf16* __restrict__ kw, bf16* __restrict__ vtw,
    const unsigned char* __restrict__ mask, u32* __restrict__ bm) {
  const int z = blockIdx.z;
  if (z == 3) {
    if (blockIdx.x == 0 && blockIdx.y == 0) detect_body(mask, bm);
    return;
  }
  if (z == 0) gemm_body<true, 0, 64, 128>(q, Wq, qw);
  else if (z == 1) gemm_body<true, 1, 64, 128>(k, Wk, kw);
  else gemm_body<true, 2, 64, 128>(v, Wv, vtw);
}

// out: 64x64 tiles, grid (64,8) = 512 blocks -> 2 blocks/CU (TLP lever).
__global__ __launch_bounds__(256) void out_kernel(const bf16* __restrict__ x,
                                                  const float* __restrict__ Wo,
                                                  float* __restrict__ out) {
  gemm_body<false, 3, 64, 64>(x, Wo, out);
}

// ---------------- attention: 128-key phases (r12 structure, byte-identical) --
__global__ __launch_bounds__(256, 2) void attn_kernel(
    const bf16* __restrict__ qw, const char* __restrict__ kw,
    const char* __restrict__ vt, const float* __restrict__ bias,
    const u32* __restrict__ bmask, bf16* __restrict__ xw) {
  __shared__ char KV[2][2][2 * kTileBytes];  // [buf][K/V][128-key tile] = 64 KB
  __shared__ u32 Ps[4][16][36];              // per-wave packed P^T rows = 9 KB
  __shared__ u32 mask_lds[64];

  const int tid = threadIdx.x;
  const int lane = tid & 63;
  const int w = tid >> 6;
  const int l16 = lane & 15, g = lane >> 4;

  const int bid = blockIdx.x;
  const int xcd = bid & 7;
  const int j = bid >> 3;                // 0..63
  const int bh = xcd * 2 + (j >> 5);     // 0..15
  const int qb = j & 31;                 // 0..31
  const int b = bh >> 3;
  const int hh = bh & 7;
  const int qr0 = qb * 64 + w * 16;

  if (tid < 64) mask_lds[tid] = bmask[b * 64 + tid];
  __syncthreads();

  const bf16* qrow = qw + ((size_t)bh * kS + qr0 + l16) * kDK;
  const bf16x8 aq0 = *(const bf16x8*)(qrow + g * 8);
  const bf16x8 aq1 = *(const bf16x8*)(qrow + 32 + g * 8);

  const float* brow = bias + ((size_t)bh * kS + qr0 + l16) * kS;
  const char* ktile = kw + (size_t)bh * kBhBytes;
  const char* vtile = vt + (size_t)bh * kBhBytes;

  f32x4 o[4] = {};
  float m_run = -__builtin_inff();
  float l_run = 0.f;
  const int swz = (l16 & 7) << 4;

  auto dma_tile = [&](int t128, int nb) {
    #pragma unroll
    for (int s2 = 0; s2 < 2; s2++) {
      const char* kg = ktile + ((size_t)t128 * 2 + s2) * kTileBytes + w * 2048 + lane * 16;
      __builtin_amdgcn_global_load_lds(
          (const __attribute__((address_space(1))) void*)kg,
          (__attribute__((address_space(3))) void*)&KV[nb][0][s2 * kTileBytes + w * 2048], 16, 0, 0);
      __builtin_amdgcn_global_load_lds(
          (const __attribute__((address_space(1))) void*)(kg + 1024),
          (__attribute__((address_space(3))) void*)&KV[nb][0][s2 * kTileBytes + w * 2048 + 1024], 16, 0, 0);
      const char* vg = vtile + ((size_t)t128 * 2 + s2) * kTileBytes + w * 2048 + lane * 16;
      __builtin_amdgcn_global_load_lds(
          (const __attribute__((address_space(1))) void*)vg,
          (__attribute__((address_space(3))) void*)&KV[nb][1][s2 * kTileBytes + w * 2048], 16, 0, 0);
      __builtin_amdgcn_global_load_lds(
          (const __attribute__((address_space(1))) void*)(vg + 1024),
          (__attribute__((address_space(3))) void*)&KV[nb][1][s2 * kTileBytes + w * 2048 + 1024], 16, 0, 0);
    }
  };
  // nontemporal bias stream: keep the 268 MB bias out of L2 so K/V stays hot.
  auto load_bias8 = [&](f32x4 (&bv)[8], int t128) {
    const float* p0 = brow + t128 * 128 + g * 4;
    asm volatile("global_load_dwordx4 %0, %1, off nt" : "=v"(bv[0]) : "v"(p0));
    asm volatile("global_load_dwordx4 %0, %1, off nt" : "=v"(bv[1]) : "v"(p0 + 16));
    asm volatile("global_load_dwordx4 %0, %1, off nt" : "=v"(bv[2]) : "v"(p0 + 32));
    asm volatile("global_load_dwordx4 %0, %1, off nt" : "=v"(bv[3]) : "v"(p0 + 48));
    asm volatile("global_load_dwordx4 %0, %1, off nt" : "=v"(bv[4]) : "v"(p0 + 64));
    asm volatile("global_load_dwordx4 %0, %1, off nt" : "=v"(bv[5]) : "v"(p0 + 80));
    asm volatile("global_load_dwordx4 %0, %1, off nt" : "=v"(bv[6]) : "v"(p0 + 96));
    asm volatile("global_load_dwordx4 %0, %1, off nt" : "=v"(bv[7]) : "v"(p0 + 112));
  };

  auto phase = [&](int t, f32x4 (&bc)[8], f32x4 (&bn)[8]) {
    const int cur = t & 1, nxt = cur ^ 1;
    const int tp = (t + 1 > 15) ? 15 : t + 1;
    dma_tile(tp, nxt);
    load_bias8(bn, tp);

    f32x4 sf[8];
    #pragma unroll
    for (int hb = 0; hb < 2; hb++) {
      const char* kb0 = &KV[cur][0][hb * kTileBytes];
      bf16x8 kf[4][2];
      #pragma unroll
      for (int nf = 0; nf < 4; nf++) {
        const int r = nf * 16 + l16;
        #pragma unroll
        for (int h = 0; h < 2; h++)
          kf[nf][h] = *(const bf16x8*)(kb0 + r * 128 + ((g * 16 + h * 64) ^ swz));
      }
      __builtin_amdgcn_s_setprio(1);
      #pragma unroll
      for (int nf = 0; nf < 4; nf++) {
        f32x4 z = {};
        z = MFMA_BF16(kf[nf][0], aq0, z);
        z = MFMA_BF16(kf[nf][1], aq1, z);
        sf[hb * 4 + nf] = z;
      }
      __builtin_amdgcn_s_setprio(0);
    }

    asm volatile("s_waitcnt vmcnt(16)" ::: "memory");
    __builtin_amdgcn_sched_barrier(0);

    const u32 wm0 = mask_lds[4 * t], wm1 = mask_lds[4 * t + 1];
    const u32 wm2 = mask_lds[4 * t + 2], wm3 = mask_lds[4 * t + 3];
    float p[8][4];
    float tmax = -__builtin_inff();
    #pragma unroll
    for (int nf = 0; nf < 8; nf++) {
      const u32 wsel = (nf < 2) ? wm0 : (nf < 4) ? wm1 : (nf < 6) ? wm2 : wm3;
      #pragma unroll
      for (int r = 0; r < 4; r++) {
        float sv = sf[nf][r] * 0.125f - bc[nf][r];
        const int bp = (nf & 1) * 16 + g * 4 + r;
        if ((wsel >> bp) & 1) sv = -__builtin_inff();
        p[nf][r] = sv;
        tmax = fmaxf(tmax, sv);
      }
    }
    tmax = fmaxf(tmax, __shfl_xor(tmax, 16, 64));
    tmax = fmaxf(tmax, __shfl_xor(tmax, 32, 64));

    const float mnew = fmaxf(m_run, tmax);
    const float scale = (m_run == -__builtin_inff()) ? 0.f : __expf(m_run - mnew);
    const float mexp = (mnew == -__builtin_inff()) ? 0.f : mnew;
    float psum = 0.f;
    #pragma unroll
    for (int nf = 0; nf < 8; nf++)
      #pragma unroll
      for (int r = 0; r < 4; r++) {
        const float pv = __expf(p[nf][r] - mexp);
        p[nf][r] = pv;
        psum += pv;
      }
    psum += __shfl_xor(psum, 16, 64);
    psum += __shfl_xor(psum, 32, 64);
    m_run = mnew;
    l_run = l_run * scale + psum;
    #pragma unroll
    for (int ni = 0; ni < 4; ni++) o[ni] *= scale;

    #pragma unroll
    for (int hb = 0; hb < 2; hb++) {
      #pragma unroll
      for (int nf = 0; nf < 4; nf++) {
        union { bf16 h2[2]; u32 u; } c0, c1;
        c0.h2[0] = (bf16)p[hb * 4 + nf][0]; c0.h2[1] = (bf16)p[hb * 4 + nf][1];
        c1.h2[0] = (bf16)p[hb * 4 + nf][2]; c1.h2[1] = (bf16)p[hb * 4 + nf][3];
        Ps[w][l16][nf * 8 + g * 2] = c0.u;
        Ps[w][l16][nf * 8 + g * 2 + 1] = c1.u;
      }
      asm volatile("s_waitcnt lgkmcnt(0)" ::: "memory");
      const char* vb0 = &KV[cur][1][hb * kTileBytes];
      bf16x8 vf[2][4];
      #pragma unroll
      for (int kb2 = 0; kb2 < 2; kb2++)
        #pragma unroll
        for (int ni = 0; ni < 4; ni++) {
          const int d = ni * 16 + l16;
          vf[kb2][ni] = *(const bf16x8*)(vb0 + d * 128 + ((kb2 * 64 + g * 16) ^ swz));
        }
      __builtin_amdgcn_s_setprio(1);
      #pragma unroll
      for (int kb2 = 0; kb2 < 2; kb2++) {
        const bf16x8 pb = *(const bf16x8*)&Ps[w][l16][kb2 * 16 + g * 4];
        #pragma unroll
        for (int ni = 0; ni < 4; ni++)
          o[ni] = MFMA_BF16(vf[kb2][ni], pb, o[ni]);
      }
      __builtin_amdgcn_s_setprio(0);
    }

    asm volatile("s_waitcnt vmcnt(8)" ::: "memory");
    __builtin_amdgcn_s_barrier();
    __builtin_amdgcn_sched_barrier(0);
  };

  f32x4 bc[8], bn[8];
  dma_tile(0, 0);
  load_bias8(bc, 0);
  asm volatile("s_waitcnt vmcnt(8)" ::: "memory");
  __builtin_amdgcn_s_barrier();
  __builtin_amdgcn_sched_barrier(0);

  for (int t = 0; t < 16; t += 2) {
    phase(t, bc, bn);
    phase(t + 1, bn, bc);
  }

  const float inv = (l_run > 0.f) ? 1.f / l_run : 0.f;
  bf16* dstp = xw + ((size_t)b * kS + qr0 + l16) * kD + hh * kDK;
  #pragma unroll
  for (int ni = 0; ni < 4; ni++) {
    union { bf16 h2[2]; u32 u; } c0, c1;
    c0.h2[0] = (bf16)(o[ni][0] * inv); c0.h2[1] = (bf16)(o[ni][1] * inv);
    c1.h2[0] = (bf16)(o[ni][2] * inv); c1.h2[1] = (bf16)(o[ni][3] * inv);
    *(u32*)&dstp[ni * 16 + g * 4] = c0.u;
    *(u32*)&dstp[ni * 16 + g * 4 + 2] = c1.u;
  }
}

extern "C" void kernel_launch(void* const* d_in, const int* in_sizes, int n_in,
                              void* d_out, int out_size, void* d_ws, size_t ws_size,
                              hipStream_t stream) {
  (void)in_sizes; (void)n_in; (void)out_size; (void)ws_size;
  const float* query = (const float*)d_in[0];
  const float* key_in = (const float*)d_in[1];
  const float* value = (const float*)d_in[2];
  const float* attnw = (const float*)d_in[3];
  const unsigned char* mask = (const unsigned char*)d_in[4];
  const float* Wq = (const float*)d_in[5];
  const float* Wk = (const float*)d_in[6];
  const float* Wv = (const float*)d_in[7];
  const float* Wo = (const float*)d_in[8];

  const size_t nqkv = (size_t)kB * kH * kS * kDK;
  size_t off = 0;
  auto alloc = [&](size_t bytes) {
    void* p = (char*)d_ws + off;
    off = (off + bytes + 255) & ~(size_t)255;
    return p;
  };
  u32* bm = (u32*)alloc(kB * kS / 32 * 4);
  bf16* q_ws = (bf16*)alloc(nqkv * 2);
  char* k_ws = (char*)alloc(nqkv * 2);
  char* vt_ws = (char*)alloc(nqkv * 2);
  bf16* x_ws = (bf16*)alloc((size_t)kB * kS * kD * 2);

  proj_kernel<<<dim3(64, 4, 4), dim3(256), 0, stream>>>(query, key_in, value, Wq, Wk, Wv,
                                                        q_ws, (bf16*)k_ws, (bf16*)vt_ws,
                                                        mask, bm);
  attn_kernel<<<dim3(512), dim3(256), 0, stream>>>(q_ws, k_ws, vt_ws, attnw, bm, x_ws);
  out_kernel<<<dim3(64, 8), dim3(256), 0, stream>>>(x_ws, Wo, (float*)d_out);
}